// Round 4
// baseline (10485.321 us; speedup 1.0000x reference)
//
#include <hip/hip_runtime.h>
#include <hip/hip_bf16.h>
#include <math.h>

// Problem constants (fixed by the reference)
#define H_DIM 4096
#define NQ    32
#define NKV   8
#define HD    128
#define GRPQ  4
#define NQKV  6144      // NQ*HD + 2*NKV*HD
#define KOFF  4096      // column offset of K region in qkv
#define VOFF  5120      // column offset of V region in qkv
#define SCALE 0.08838834764831844f   // 128^-0.5

static __device__ __forceinline__ float bf2f(unsigned short u) {
    return __uint_as_float(((unsigned int)u) << 16);
}

// 4-element vector load -> float4, overloaded on source dtype.
static __device__ __forceinline__ float4 load4(const float* p) {
    return *reinterpret_cast<const float4*>(p);
}
static __device__ __forceinline__ float4 load4(const unsigned short* p) {
    ushort4 v = *reinterpret_cast<const ushort4*>(p);
    return make_float4(bf2f(v.x), bf2f(v.y), bf2f(v.z), bf2f(v.w));
}

// Scalar store, overloaded on destination dtype (fp32 or bf16-bits).
static __device__ __forceinline__ void store1(float* p, float v) { *p = v; }
static __device__ __forceinline__ void store1(unsigned short* p, float v) {
    *p = __bfloat16_as_ushort(__float2bfloat16(v));
}

// ---------------------------------------------------------------------------
// Generic GEMM: C[M,N] = A[M,K] @ B[K,N], row-major, fp32 accumulate.
// A/B/C dtypes templated (float or bf16-as-ushort).
// 128x128 block tile, BK=16, 256 threads, 8x8 microtile per thread.
// ---------------------------------------------------------------------------
#define BM 128
#define BN 128
#define BK 16
#define LPAD 4

template <typename TA, typename TB, typename TC>
__global__ __launch_bounds__(256) void gemm_f32acc(
    const TA* __restrict__ A,
    const TB* __restrict__ B,
    TC* __restrict__ C,
    int M, int N, int K)
{
    __shared__ float As[BK][BM + LPAD];
    __shared__ float Bs[BK][BN + LPAD];

    const int tid = threadIdx.x;
    const int bm  = blockIdx.y * BM;
    const int bn  = blockIdx.x * BN;
    const int tx  = tid & 15;   // 0..15 -> 8 cols each
    const int ty  = tid >> 4;   // 0..15 -> 8 rows each

    float acc[8][8];
#pragma unroll
    for (int i = 0; i < 8; ++i)
#pragma unroll
        for (int j = 0; j < 8; ++j) acc[i][j] = 0.0f;

    for (int k0 = 0; k0 < K; k0 += BK) {
        // Stage A tile: BM x BK (= 512 float4 quads)
        for (int q = tid; q < (BM * BK) / 4; q += 256) {
            int row = q >> 2;            // BK/4 = 4 quads per row
            int kq  = (q & 3) << 2;
            float4 v = load4(&A[(size_t)(bm + row) * K + k0 + kq]);
            As[kq + 0][row] = v.x;
            As[kq + 1][row] = v.y;
            As[kq + 2][row] = v.z;
            As[kq + 3][row] = v.w;
        }
        // Stage B tile: BK x BN (= 512 quads), coalesced along N
        for (int q = tid; q < (BK * BN) / 4; q += 256) {
            int k = q >> 5;              // BN/4 = 32 quads per row
            int n = (q & 31) << 2;
            float4 v = load4(&B[(size_t)(k0 + k) * N + bn + n]);
            Bs[k][n + 0] = v.x;
            Bs[k][n + 1] = v.y;
            Bs[k][n + 2] = v.z;
            Bs[k][n + 3] = v.w;
        }
        __syncthreads();

#pragma unroll
        for (int k = 0; k < BK; ++k) {
            float a[8], b[8];
#pragma unroll
            for (int i = 0; i < 8; ++i) a[i] = As[k][ty * 8 + i];
#pragma unroll
            for (int j = 0; j < 8; ++j) b[j] = Bs[k][tx * 8 + j];
#pragma unroll
            for (int i = 0; i < 8; ++i)
#pragma unroll
                for (int j = 0; j < 8; ++j) acc[i][j] += a[i] * b[j];
        }
        __syncthreads();
    }

#pragma unroll
    for (int i = 0; i < 8; ++i) {
        size_t r = (size_t)(bm + ty * 8 + i);
#pragma unroll
        for (int j = 0; j < 8; ++j) {
            int c = bn + tx * 8 + j;
            store1(&C[r * N + c], acc[i][j]);
        }
    }
}

// ---------------------------------------------------------------------------
// RoPE applied in place to the Q and K regions of qkv (S x 6144, bf16).
// Heads 0..31 = Q heads (cols 0..4095); heads 32..39 = K heads (cols
// 4096..5119) — head*128 addresses both since 32*128 == 4096.
//
// positions may be int32 or int64; for arange data an int32 view has
// p32[1]==1 (int32) vs p32[1]==0 (LE int64) — detected at runtime.
// (Round-3 evidence: identical error with/without this => int32 in practice.)
// ---------------------------------------------------------------------------
__global__ __launch_bounds__(256) void rope_kernel(
    unsigned short* __restrict__ qkv,
    const int* __restrict__ pos32,
    int S)
{
    int idx = blockIdx.x * 256 + threadIdx.x;
    int total = S * (NQ + NKV) * (HD / 2);
    if (idx >= total) return;

    int j    = idx & 63;
    int head = (idx >> 6) % (NQ + NKV);
    int s    = idx / (64 * (NQ + NKV));

    const bool is64 = (pos32[1] == 0);      // int64 little-endian arange
    int pos = is64 ? pos32[2 * s] : pos32[s];

    unsigned short* row = qkv + (size_t)s * NQKV + head * HD;
    float x1 = bf2f(row[j]);
    float x2 = bf2f(row[j + 64]);

    float p = (float)pos;
    float inv_freq = powf(10000.0f, -((float)j) * (1.0f / 64.0f));
    float f = p * inv_freq;
    float sn, cs;
    sincosf(f, &sn, &cs);   // accurate version (full arg reduction)

    row[j]      = __bfloat16_as_ushort(__float2bfloat16(x1 * cs - x2 * sn));
    row[j + 64] = __bfloat16_as_ushort(__float2bfloat16(x2 * cs + x1 * sn));
}

// ---------------------------------------------------------------------------
// Flash-style causal GQA attention. One block per (q-head, 32-row q tile).
// K/V tiles (32 x 128) staged in LDS; online softmax; O in registers.
// ---------------------------------------------------------------------------
#define BQ 32
#define BT 32

__global__ __launch_bounds__(256) void attn_kernel(
    const unsigned short* __restrict__ qkv,   // S x 6144 bf16 bits
    unsigned short* __restrict__ attn_out,    // S x 4096 bf16 bits
    int S)
{
    __shared__ float Qs[BQ][HD + LPAD];
    __shared__ float Ks[BT][HD + LPAD];
    __shared__ float Vs[BT][HD + LPAD];
    __shared__ float Ss[BQ][BT + 1];
    __shared__ float m_s[BQ], l_s[BQ], al_s[BQ];

    const int tid = threadIdx.x;
    const int h   = blockIdx.y;       // query head
    const int g   = h >> 2;           // kv head (GRP=4)
    const int s0  = blockIdx.x * BQ;

    // Load Q tile, pre-scaled by 1/sqrt(D)
    for (int q = tid; q < (BQ * HD) / 4; q += 256) {
        int i = q >> 5;               // 32 quads per row
        int d = (q & 31) << 2;
        float4 v = load4(&qkv[(size_t)(s0 + i) * NQKV + h * HD + d]);
        Qs[i][d + 0] = v.x * SCALE;
        Qs[i][d + 1] = v.y * SCALE;
        Qs[i][d + 2] = v.z * SCALE;
        Qs[i][d + 3] = v.w * SCALE;
    }
    if (tid < BQ) { m_s[tid] = -1e9f; l_s[tid] = 0.0f; }

    float o[16];
#pragma unroll
    for (int dd = 0; dd < 16; ++dd) o[dd] = 0.0f;
    const int oi = tid >> 3;          // O row (0..31)
    const int od = (tid & 7) << 4;    // O col base (16 floats)

    for (int t0 = 0; t0 <= s0; t0 += BT) {
        __syncthreads();  // prev PV done (also covers Q load / m,l init)

        // Stage K and V tiles
        for (int q = tid; q < (BT * HD) / 4; q += 256) {
            int j = q >> 5;
            int d = (q & 31) << 2;
            size_t base = (size_t)(t0 + j) * NQKV + g * HD;
            float4 kv = load4(&qkv[base + KOFF + d]);
            float4 vv = load4(&qkv[base + VOFF + d]);
            Ks[j][d + 0] = kv.x; Ks[j][d + 1] = kv.y;
            Ks[j][d + 2] = kv.z; Ks[j][d + 3] = kv.w;
            Vs[j][d + 0] = vv.x; Vs[j][d + 1] = vv.y;
            Vs[j][d + 2] = vv.z; Vs[j][d + 3] = vv.w;
        }
        __syncthreads();

        // Scores: thread -> row i = tid/8, 4 cols starting at (tid%8)*4
        {
            int i  = tid >> 3;
            int j0 = (tid & 7) << 2;
            float sc0 = 0.f, sc1 = 0.f, sc2 = 0.f, sc3 = 0.f;
            for (int d = 0; d < HD; d += 4) {
                float4 qv = *reinterpret_cast<const float4*>(&Qs[i][d]);
                float4 k0 = *reinterpret_cast<const float4*>(&Ks[j0 + 0][d]);
                float4 k1 = *reinterpret_cast<const float4*>(&Ks[j0 + 1][d]);
                float4 k2 = *reinterpret_cast<const float4*>(&Ks[j0 + 2][d]);
                float4 k3 = *reinterpret_cast<const float4*>(&Ks[j0 + 3][d]);
                sc0 += qv.x * k0.x + qv.y * k0.y + qv.z * k0.z + qv.w * k0.w;
                sc1 += qv.x * k1.x + qv.y * k1.y + qv.z * k1.z + qv.w * k1.w;
                sc2 += qv.x * k2.x + qv.y * k2.y + qv.z * k2.z + qv.w * k2.w;
                sc3 += qv.x * k3.x + qv.y * k3.y + qv.z * k3.z + qv.w * k3.w;
            }
            int srow = s0 + i;
            if (t0 + j0 + 0 > srow) sc0 = -1e9f;
            if (t0 + j0 + 1 > srow) sc1 = -1e9f;
            if (t0 + j0 + 2 > srow) sc2 = -1e9f;
            if (t0 + j0 + 3 > srow) sc3 = -1e9f;
            Ss[i][j0 + 0] = sc0; Ss[i][j0 + 1] = sc1;
            Ss[i][j0 + 2] = sc2; Ss[i][j0 + 3] = sc3;
        }
        __syncthreads();

        // Online softmax update: one thread per q row
        if (tid < BQ) {
            int i = tid;
            float mold = m_s[i];
            float mnew = mold;
            for (int j = 0; j < BT; ++j) mnew = fmaxf(mnew, Ss[i][j]);
            float alpha = __expf(mold - mnew);
            float l = l_s[i] * alpha;
            for (int j = 0; j < BT; ++j) {
                float p = __expf(Ss[i][j] - mnew);
                Ss[i][j] = p;
                l += p;
            }
            m_s[i] = mnew; l_s[i] = l; al_s[i] = alpha;
        }
        __syncthreads();

        // PV accumulate: thread owns (row oi, 16 cols at od)
        {
            float alpha = al_s[oi];
#pragma unroll
            for (int dd = 0; dd < 16; ++dd) o[dd] *= alpha;
            for (int j = 0; j < BT; ++j) {
                float p = Ss[oi][j];
                float4 v0 = *reinterpret_cast<const float4*>(&Vs[j][od + 0]);
                float4 v1 = *reinterpret_cast<const float4*>(&Vs[j][od + 4]);
                float4 v2 = *reinterpret_cast<const float4*>(&Vs[j][od + 8]);
                float4 v3 = *reinterpret_cast<const float4*>(&Vs[j][od + 12]);
                o[0]  += p * v0.x; o[1]  += p * v0.y; o[2]  += p * v0.z; o[3]  += p * v0.w;
                o[4]  += p * v1.x; o[5]  += p * v1.y; o[6]  += p * v1.z; o[7]  += p * v1.w;
                o[8]  += p * v2.x; o[9]  += p * v2.y; o[10] += p * v2.z; o[11] += p * v2.w;
                o[12] += p * v3.x; o[13] += p * v3.y; o[14] += p * v3.z; o[15] += p * v3.w;
            }
        }
    }

    // Epilogue: normalize and store bf16
    float linv = 1.0f / l_s[oi];
    unsigned short* dst = attn_out + (size_t)(s0 + oi) * (NQ * HD) + h * HD + od;
#pragma unroll
    for (int dd = 0; dd < 16; ++dd)
        dst[dd] = __bfloat16_as_ushort(__float2bfloat16(o[dd] * linv));
}

// ---------------------------------------------------------------------------
extern "C" void kernel_launch(void* const* d_in, const int* in_sizes, int n_in,
                              void* d_out, int out_size, void* d_ws, size_t ws_size,
                              hipStream_t stream)
{
    const int*   positions = (const int*)d_in[0];     // int32 (detected in-kernel)
    const float* hidden    = (const float*)d_in[1];   // S x 4096 fp32
    const float* w_qkv     = (const float*)d_in[2];   // 4096 x 6144 fp32
    const float* w_o       = (const float*)d_in[3];   // 4096 x 4096 fp32
    const int S = in_sizes[0];

    // Workspace: qkv (S x 6144 bf16) then attn (S x 4096 bf16) = 80 MB total
    unsigned short* qkv  = (unsigned short*)d_ws;
    unsigned short* attn = qkv + (size_t)S * NQKV;

    // 1) QKV projection (fp32 x fp32 -> bf16 ws)
    dim3 g1(NQKV / BN, S / BM);
    gemm_f32acc<float, float, unsigned short><<<g1, 256, 0, stream>>>(
        hidden, w_qkv, qkv, S, NQKV, H_DIM);

    // 2) RoPE on Q and K regions (in place, bf16)
    int total = S * (NQ + NKV) * (HD / 2);
    rope_kernel<<<(total + 255) / 256, 256, 0, stream>>>(qkv, positions, S);

    // 3) Causal GQA flash attention (bf16 -> bf16 ws)
    dim3 g3(S / BQ, NQ);
    attn_kernel<<<g3, 256, 0, stream>>>(qkv, attn, S);

    // 4) Output projection -> d_out (bf16 x fp32 -> FP32 out; the reference's
    //    output dtype is float32, so d_out is float*)
    dim3 g4(H_DIM / BN, S / BM);
    gemm_f32acc<unsigned short, float, float><<<g4, 256, 0, stream>>>(
        attn, w_o, (float*)d_out, S, H_DIM, H_DIM);
}